// Round 4
// baseline (272.760 us; speedup 1.0000x reference)
//
#include <hip/hip_runtime.h>
#include <hip/hip_bf16.h>

// fasterRCNN box decode + per-class argmax region pick.
// Inputs (fp32): boxes (N,4), box_deltas (N,28), scores (N,7), im_info (3)
// Output (fp32, concat): pred_boxes (N*28), region_g (5), region_l (5)
//
// R3: ROW-PER-THREAD redesign. R0 (pair-per-thread, VGPR12) and R2 (ITEMS=4
// unroll, VGPR32) both sat at ~83us ~ 3.1 TB/s effective — the per-item
// volatile-LDS-precheck/atomic chain and duplicated boxes/scores streams are
// the suspects, not raw MLP. Now each thread owns a row:
//   - boxes[row]: ONE coalesced float4 per thread (was 7x duplicated)
//   - deltas row: 7 float4 loads, lane stride 112B (all bytes used, L1-dense)
//   - scores: 6 dwords (class 0 never used by reference -> 4MB less fetch)
//   - w/h/cx/cy computed once per row (VALU / 7)
//   - per-class argmax keys in REGISTERS (static unroll index), zero LDS in
//     the hot loop; block reduce = 6-slot wave shuffle-max + 4 LDS atomics,
//     once per kernel.
// key = (monotone(score)<<32) | (0xFFFFFFFF - row)  [first-index tie-break]
// Finalize kernel (1 block) reduces per-block winners, gathers from pred.

#define THRESH_F 0.05f
#define TPB 256
#define RPT 2            // rows per thread, sequential
#define ROWS_PER_BLOCK (TPB * RPT)

typedef unsigned long long ull;

__device__ __forceinline__ unsigned map_float(unsigned bits) {
    // monotone map float bits -> unsigned (order-preserving)
    return (bits & 0x80000000u) ? ~bits : (bits | 0x80000000u);
}

__global__ __launch_bounds__(TPB) void decode_pick_kernel(
    const float4* __restrict__ boxes,
    const float4* __restrict__ deltas,
    const float*  __restrict__ scores,
    const float*  __restrict__ im_info,
    float4*       __restrict__ pred,
    ull*          __restrict__ blockbest,
    int N)
{
    const int tid = threadIdx.x;
    const float maxX = im_info[1] - 1.0f;   // W-1
    const float maxY = im_info[0] - 1.0f;   // H-1

    ull best[6];
    #pragma unroll
    for (int s = 0; s < 6; ++s) best[s] = 0ULL;

    for (int r = 0; r < RPT; ++r) {
        const int row = blockIdx.x * ROWS_PER_BLOCK + r * TPB + tid;
        if (row >= N) continue;

        // ---- batched loads (15 independent requests in flight) ----
        const float4 b = boxes[row];
        const float4* __restrict__ drow = deltas + (size_t)row * 7;
        float4 d[7];
        #pragma unroll
        for (int c = 0; c < 7; ++c) d[c] = drow[c];
        const float* __restrict__ srow = scores + (size_t)row * 7;
        float s[6];
        #pragma unroll
        for (int c = 0; c < 6; ++c) s[c] = srow[c + 1];   // class 0 unused

        // ---- per-row invariants ----
        const float w  = b.z - b.x + 1.0f;
        const float h  = b.w - b.y + 1.0f;
        const float cx = b.x + 0.5f * w;
        const float cy = b.y + 0.5f * h;

        float4* __restrict__ prow = pred + (size_t)row * 7;
        const unsigned negrow = 0xFFFFFFFFu - (unsigned)row;

        #pragma unroll
        for (int c = 0; c < 7; ++c) {
            const float pcx = (d[c].x * 0.1f) * w + cx;
            const float pcy = (d[c].y * 0.1f) * h + cy;
            const float pw  = __expf(d[c].z * 0.2f) * w * 0.5f;
            const float ph  = __expf(d[c].w * 0.2f) * h * 0.5f;
            float4 o;
            o.x = fminf(fmaxf(pcx - pw, 0.0f), maxX);
            o.y = fminf(fmaxf(pcy - ph, 0.0f), maxY);
            o.z = fminf(fmaxf(pcx + pw, 0.0f), maxX);
            o.w = fminf(fmaxf(pcy + ph, 0.0f), maxY);
            prow[c] = o;

            if (c >= 1) {
                const float m = (s[c - 1] > THRESH_F) ? s[c - 1] : -1.0f;
                const ull key = ((ull)map_float(__float_as_uint(m)) << 32) |
                                (ull)negrow;
                if (key > best[c - 1]) best[c - 1] = key;   // static slot index
            }
        }
    }

    // ---- once-per-kernel reduction: wave shuffle-max then LDS ----
    #pragma unroll
    for (int slot = 0; slot < 6; ++slot) {
        #pragma unroll
        for (int off = 32; off > 0; off >>= 1) {
            const ull v = __shfl_xor(best[slot], off, 64);
            if (v > best[slot]) best[slot] = v;
        }
    }

    __shared__ ull sbest[6];
    if (tid < 6) sbest[tid] = 0ULL;
    __syncthreads();
    if ((tid & 63) == 0) {             // one lane per wave
        #pragma unroll
        for (int slot = 0; slot < 6; ++slot)
            if (best[slot] != 0ULL) atomicMax(&sbest[slot], best[slot]);
    }
    __syncthreads();
    if (tid < 6)
        blockbest[(size_t)blockIdx.x * 6 + tid] = sbest[tid];
}

__global__ __launch_bounds__(TPB) void finalize_kernel(
    const ull* __restrict__ blockbest,
    int nblocks,
    const float* __restrict__ pred,
    float*       __restrict__ regions)   // d_out + N*28, 10 floats
{
    __shared__ ull red[TPB];
    __shared__ ull fin[6];
    const int tid = threadIdx.x;

    for (int slot = 0; slot < 6; ++slot) {
        ull k = 0ULL;
        for (int j = tid; j < nblocks; j += TPB) {
            const ull v = blockbest[(size_t)j * 6 + slot];
            if (v > k) k = v;
        }
        red[tid] = k;
        __syncthreads();
        for (int off = TPB / 2; off > 0; off >>= 1) {
            if (tid < off) {
                const ull v = red[tid + off];
                if (v > red[tid]) red[tid] = v;
            }
            __syncthreads();
        }
        if (tid == 0) fin[slot] = red[0];
        __syncthreads();
    }

    if (tid == 0) {
        for (int g = 0; g < 2; ++g) {
            float scores_[3];
            unsigned idx_[3];
            float bestScore = -1e30f;
            int bestJ = 0;
            for (int j = 0; j < 3; ++j) {
                const ull key = fin[g * 3 + j];
                const unsigned hi = (unsigned)(key >> 32);
                const unsigned bits = (hi & 0x80000000u) ? (hi & 0x7FFFFFFFu) : ~hi;
                scores_[j] = __uint_as_float(bits);
                idx_[j] = 0xFFFFFFFFu - (unsigned)(key & 0xFFFFFFFFu);
                if (scores_[j] > bestScore) { bestScore = scores_[j]; bestJ = j; }
            }
            const int c = g * 3 + bestJ + 1;
            const unsigned i = idx_[bestJ];
            const float* pb = pred + (size_t)i * 28 + (size_t)c * 4;
            float* r = regions + g * 5;
            r[0] = pb[0];
            r[1] = pb[1];
            r[2] = pb[2];
            r[3] = pb[3];
            r[4] = scores_[bestJ];
        }
    }
}

extern "C" void kernel_launch(void* const* d_in, const int* in_sizes, int n_in,
                              void* d_out, int out_size, void* d_ws, size_t ws_size,
                              hipStream_t stream) {
    const float* boxes   = (const float*)d_in[0];
    const float* deltas  = (const float*)d_in[1];
    const float* scores  = (const float*)d_in[2];
    const float* im_info = (const float*)d_in[3];

    const int N = in_sizes[0] / 4;       // 1,000,000 rows

    float* out = (float*)d_out;
    float* regions = out + (size_t)N * 28;

    ull* blockbest = (ull*)d_ws;         // nblk*6*8 bytes (~94 KB)

    const int nblk = (N + ROWS_PER_BLOCK - 1) / ROWS_PER_BLOCK;   // 1954
    decode_pick_kernel<<<nblk, TPB, 0, stream>>>(
        (const float4*)boxes, (const float4*)deltas, scores, im_info,
        (float4*)out, blockbest, N);

    finalize_kernel<<<1, TPB, 0, stream>>>(blockbest, nblk, out, regions);
}